// Round 11
// baseline (637.490 us; speedup 1.0000x reference)
//
#include <hip/hip_runtime.h>

#define BN 100000
#define DD 128
#define EN 500000
#define NM 4096
#define NROWS (BN + NM)     // 104096
#define GEMM_NB ((NROWS + 63) / 64)       // 1627 gemm blocks (64 rows each)
#define HIST_NB ((EN / 4 + 255) / 256)    // 489 hist blocks (fused in gemm tail)
#define SCHUNK 1024
#define SNB ((BN + SCHUNK - 1) / SCHUNK)  // 98 scan blocks (all co-resident)
#define AGG_NB (BN / 8)                   // 12500 aggregate blocks

// ---- ws layout (4-byte units) ----
#define OFF_H      0
#define LEN_H      ((size_t)NROWS * DD)           // 13,324,288
#define OFF_CNT    (LEN_H)                        // 100000 ints (zeroed by k_prep)
#define OFF_SLOTS  (OFF_CNT + BN)                 // 256 f xbnorm
#define OFF_ISLOTS (OFF_SLOTS + 256)              // 256 f info
#define OFF_RS     (OFF_ISLOTS + 256)             // 100001 ints
#define OFF_NEXT   (OFF_RS + BN + 1)              // 100000 ints
#define OFF_EQ     ((OFF_NEXT + BN + 1) & ~(size_t)1)  // int2[EN], 8B-aligned
#define OFF_BS     (OFF_EQ + 2 * (size_t)EN)      // 128 ints: [1]=agg done ctr
// packed W (16384 f) + lookback state (98 ull) live INSIDE the eq region:
// written early, dead before slot-scatter writes eq. Zero ws growth.
#define OFF_WP     ((OFF_EQ + 3) & ~(size_t)3)
#define OFF_ST     (OFF_WP + 16384)

typedef __attribute__((ext_vector_type(8))) short short8;      // 8 bf16 = 4 VGPR
typedef __attribute__((ext_vector_type(16))) float f32x16;     // MFMA 32x32 acc

// split fp32 -> bf16 hi (truncate) + bf16 lo (RNE of residual); pack pairs.
__device__ __forceinline__ void split2(float x0, float x1, unsigned& hi, unsigned& lo) {
    const unsigned b0 = __float_as_uint(x0), b1 = __float_as_uint(x1);
    const unsigned h0 = b0 & 0xFFFF0000u, h1 = b1 & 0xFFFF0000u;
    hi = (h0 >> 16) | h1;
    const float r0 = x0 - __uint_as_float(h0);
    const float r1 = x1 - __uint_as_float(h1);
    unsigned c0 = __float_as_uint(r0), c1 = __float_as_uint(r1);
    c0 += 0x7FFFu + ((c0 >> 16) & 1u);
    c1 += 0x7FFFu + ((c1 >> 16) & 1u);
    lo = (c0 >> 16) | (c1 & 0xFFFF0000u);
}

// ---------------- prep: zero cnt/slots/islots + scan state + counters; pack W
__global__ void k_prep(const float* __restrict__ W, short8* __restrict__ wp,
                       int4* __restrict__ zero_base, unsigned long long* __restrict__ st,
                       int* __restrict__ ctrs) {
    const int gid = blockIdx.x * 256 + threadIdx.x;
    if (gid < (BN + 512) / 4) zero_base[gid] = make_int4(0, 0, 0, 0);
    if (gid < SNB) st[gid] = 0ULL;
    if (gid == 0) { ctrs[0] = 0; ctrs[1] = 0; }
    if (gid < 2048) {
        const int lane_c = gid & 63;
        const int ct_c = (gid >> 6) & 3;
        const int ks_c = (gid >> 8) & 7;
        const int col = ct_c * 32 + (lane_c & 31);
        const int kb = ks_c * 16 + (lane_c >> 5) * 8;
        union { unsigned u[4]; short8 v; } uh, ul;
#pragma unroll
        for (int j2 = 0; j2 < 4; j2++) {
            const float x0 = W[(size_t)(kb + 2 * j2) * DD + col];
            const float x1 = W[(size_t)(kb + 2 * j2 + 1) * DD + col];
            split2(x0, x1, uh.u[j2], ul.u[j2]);
        }
        wp[((0 * 8 + ks_c) * 4 + ct_c) * 64 + lane_c] = uh.v;
        wp[((1 * 8 + ks_c) * 4 + ct_c) * 64 + lane_c] = ul.v;
    }
}

// ---------------- GEMM via split-bf16 MFMA + fused xb_norm + fused hist tail
// Per-wave tile 32 rows x 64 cols (acc = 32 AGPR); block = 64 rows x 128 cols.
// A fp32-staged 4 K-steps deep; B from pre-packed global Wp (L2-resident).
__launch_bounds__(256, 4)
__global__ void k_gemm(const float* __restrict__ X_B, const float* __restrict__ codebook,
                       const short8* __restrict__ wp, const float* __restrict__ warm,
                       float* __restrict__ h, float* __restrict__ slots,
                       const int* __restrict__ edge_dst, int* __restrict__ cnt) {
    if (blockIdx.x >= GEMM_NB) {
        // ---- histogram by dst (int4), block-uniform branch, no barriers ----
        const int e4 = (blockIdx.x - GEMM_NB) * 256 + threadIdx.x;
        if (e4 < EN / 4) {
            const int4 d = ((const int4*)edge_dst)[e4];
            atomicAdd(&cnt[d.x], 1);
            atomicAdd(&cnt[d.y], 1);
            atomicAdd(&cnt[d.z], 1);
            atomicAdd(&cnt[d.w], 1);
        }
        return;
    }

    const int tid = threadIdx.x;
    const float wu = *warm;
    const int lane = tid & 63;
    const int w = tid >> 6;
    const int ch = w & 1;
    const int r0 = blockIdx.x * 64;
    const int rw0 = r0 + (w >> 1) * 32;
    const int rr = lane & 31;
    const int kh = lane >> 5;
    const int row = rw0 + rr;

    const bool is_x = (row < BN);
    const bool valid = (row < NROWS);
    const float* src = is_x ? (X_B + (size_t)row * DD)
                            : (codebook + (size_t)(valid ? (row - BN) : 0) * DD);
    const float scale = is_x ? 1.f : (valid ? wu : 0.f);
    const float* srck = src + kh * 8;
    const short8* wpl = wp + lane;
    const int ct0 = ch * 2, ct1 = ch * 2 + 1;

    f32x16 acc0 = {}, acc1 = {};
    float ss = 0.f;

    float4 a[8];
#pragma unroll
    for (int i = 0; i < 8; i++)
        a[i] = *(const float4*)(srck + (i >> 1) * 16 + (i & 1) * 4);

#pragma unroll
    for (int ks = 0; ks < 8; ks++) {
        const int sl = (ks & 3) * 2;
        float4 q0 = a[sl], q1 = a[sl + 1];
        if (ks < 4) {
            a[sl]     = *(const float4*)(srck + (ks + 4) * 16);
            a[sl + 1] = *(const float4*)(srck + (ks + 4) * 16 + 4);
        }
        q0.x *= scale; q0.y *= scale; q0.z *= scale; q0.w *= scale;
        q1.x *= scale; q1.y *= scale; q1.z *= scale; q1.w *= scale;
        ss += q0.x * q0.x + q0.y * q0.y + q0.z * q0.z + q0.w * q0.w +
              q1.x * q1.x + q1.y * q1.y + q1.z * q1.z + q1.w * q1.w;

        union { unsigned u[4]; short8 v; } ah, al;
        split2(q0.x, q0.y, ah.u[0], al.u[0]);
        split2(q0.z, q0.w, ah.u[1], al.u[1]);
        split2(q1.x, q1.y, ah.u[2], al.u[2]);
        split2(q1.z, q1.w, ah.u[3], al.u[3]);

        const short8 bh0 = wpl[((0 * 8 + ks) * 4 + ct0) * 64];
        const short8 bh1 = wpl[((0 * 8 + ks) * 4 + ct1) * 64];
        const short8 bl0 = wpl[((1 * 8 + ks) * 4 + ct0) * 64];
        const short8 bl1 = wpl[((1 * 8 + ks) * 4 + ct1) * 64];

        acc0 = __builtin_amdgcn_mfma_f32_32x32x16_bf16(ah.v, bh0, acc0, 0, 0, 0);
        acc1 = __builtin_amdgcn_mfma_f32_32x32x16_bf16(ah.v, bh1, acc1, 0, 0, 0);
        acc0 = __builtin_amdgcn_mfma_f32_32x32x16_bf16(al.v, bh0, acc0, 0, 0, 0);
        acc1 = __builtin_amdgcn_mfma_f32_32x32x16_bf16(al.v, bh1, acc1, 0, 0, 0);
        acc0 = __builtin_amdgcn_mfma_f32_32x32x16_bf16(ah.v, bl0, acc0, 0, 0, 0);
        acc1 = __builtin_amdgcn_mfma_f32_32x32x16_bf16(ah.v, bl1, acc1, 0, 0, 0);
        acc0 = __builtin_amdgcn_mfma_f32_32x32x16_bf16(al.v, bl0, acc0, 0, 0, 0);
        acc1 = __builtin_amdgcn_mfma_f32_32x32x16_bf16(al.v, bl1, acc1, 0, 0, 0);
    }

    const int colbase = ch * 64 + (lane & 31);
    const int mbase = 4 * (lane >> 5);
    const bool fullblk = (r0 + 64 <= NROWS);
    if (fullblk) {
#pragma unroll
        for (int r = 0; r < 16; r++) {
            const int m = (r & 3) + 8 * (r >> 2) + mbase;
            float* hp = &h[(size_t)(rw0 + m) * DD + colbase];
            hp[0]  = acc0[r];
            hp[32] = acc1[r];
        }
    } else {
#pragma unroll
        for (int r = 0; r < 16; r++) {
            const int m = (r & 3) + 8 * (r >> 2) + mbase;
            if (rw0 + m < NROWS) {
                float* hp = &h[(size_t)(rw0 + m) * DD + colbase];
                hp[0]  = acc0[r];
                hp[32] = acc1[r];
            }
        }
    }

    float p = ss + __shfl_xor(ss, 32);
    float local = 0.f;
    if (ch == 0 && lane < 32 && row < BN) local = sqrtf(p);
#pragma unroll
    for (int off = 32; off > 0; off >>= 1) local += __shfl_down(local, off);
    if (lane == 0 && ch == 0) unsafeAtomicAdd(&slots[blockIdx.x & 255], local);
}

// ---------------- single-pass decoupled-lookback scan (replaces scan1/2/3) ----
// 98 blocks (all co-resident by capacity => progress guaranteed regardless of
// dispatch order). Block b scans cnt[b*1024..], publishes {state,value} packed
// in one 64-bit agent-scope atomic; spins only on lower-ID blocks.
__launch_bounds__(256)
__global__ void k_scan(const int* __restrict__ cnt, int* __restrict__ rs,
                       int* __restrict__ next, unsigned long long* __restrict__ st) {
    const int bid = blockIdx.x, tid = threadIdx.x;
    const int i0 = bid * SCHUNK + tid * 4;
    int4 v = make_int4(0, 0, 0, 0);
    if (i0 + 3 < BN) {
        v = *(const int4*)&cnt[i0];
    } else if (i0 < BN) {
        v.x = cnt[i0];
        if (i0 + 1 < BN) v.y = cnt[i0 + 1];
        if (i0 + 2 < BN) v.z = cnt[i0 + 2];
    }
    const int tsum = v.x + v.y + v.z + v.w;

    // inclusive wave scan of per-thread sums
    int s = tsum;
#pragma unroll
    for (int off = 1; off < 64; off <<= 1) {
        const int n = __shfl_up(s, off);
        if ((tid & 63) >= off) s += n;
    }
    __shared__ int wsum[4];
    __shared__ int sprefix;
    if ((tid & 63) == 63) wsum[tid >> 6] = s;
    __syncthreads();
    int woff = 0;
    {
        const int wv = tid >> 6;
        if (wv > 0) woff += wsum[0];
        if (wv > 1) woff += wsum[1];
        if (wv > 2) woff += wsum[2];
    }
    if (tid == 0) {
        const int total = wsum[0] + wsum[1] + wsum[2] + wsum[3];
        const unsigned long long pkt = (bid == 0)
            ? ((2ULL << 32) | (unsigned)total)
            : ((1ULL << 32) | (unsigned)total);
        __hip_atomic_store(&st[bid], pkt, __ATOMIC_RELAXED, __HIP_MEMORY_SCOPE_AGENT);
        int run = 0;
        if (bid > 0) {
            int pb = bid - 1;
            while (true) {
                const unsigned long long q = __hip_atomic_load(
                    &st[pb], __ATOMIC_RELAXED, __HIP_MEMORY_SCOPE_AGENT);
                const unsigned stt = (unsigned)(q >> 32);
                if (stt == 0u) { __builtin_amdgcn_s_sleep(1); continue; }
                run += (int)(q & 0xffffffffULL);
                if (stt == 2u) break;
                --pb;
            }
            __hip_atomic_store(&st[bid], (2ULL << 32) | (unsigned)(run + total),
                               __ATOMIC_RELAXED, __HIP_MEMORY_SCOPE_AGENT);
        }
        sprefix = run;
    }
    __syncthreads();
    const int ex = sprefix + woff + (s - tsum);
    const int e0 = ex, e1 = ex + v.x, e2 = e1 + v.y, e3 = e2 + v.z;
    if (i0 < BN)     { rs[i0]     = e0; next[i0]     = e0; }
    if (i0 + 1 < BN) { rs[i0 + 1] = e1; next[i0 + 1] = e1; }
    if (i0 + 2 < BN) { rs[i0 + 2] = e2; next[i0 + 2] = e2; }
    if (i0 + 3 < BN) { rs[i0 + 3] = e3; next[i0 + 3] = e3; }
    if (bid == 0 && tid == 0) rs[BN] = EN;
}

// ---------------- slot-scatter edges into CSR order (packed int2) --------
__global__ void k_slot(const int* __restrict__ edge_dst, const int* __restrict__ edge_src,
                       const float* __restrict__ ew, const int* __restrict__ cidx,
                       int* __restrict__ next, int2* __restrict__ eq) {
    const int e = blockIdx.x * 256 + threadIdx.x;
    if (e < EN) {
        const int d = edge_dst[e];
        const int s = edge_src[e];
        const int p = atomicAdd(&next[d], 1);
        const int se = (s < BN) ? s : (BN + cidx[s]);
        eq[p] = make_int2(se, __float_as_int(ew[e]));
    }
}

// ---------------- fused aggregate + info + last-block finalize ----------------
// 2 rows per wave (32-lane groups), float4 per lane; the LAST block (device-
// scope counter + fence) reduces slots/islots and writes the scalar tail.
__launch_bounds__(256)
__global__ void k_agg(const float* __restrict__ h, const int* __restrict__ rs,
                      const int2* __restrict__ eq,
                      const float* __restrict__ b, const float* __restrict__ grad,
                      float* __restrict__ out, float* __restrict__ islots,
                      const float* __restrict__ slots, const float* __restrict__ warm,
                      int* __restrict__ ctrs) {
    const int tid = threadIdx.x;
    const int lane = tid & 63;
    const int wave = tid >> 6;
    const int grp  = lane >> 5;
    const int l    = lane & 31;
    const int gb   = grp << 5;
    const int row  = blockIdx.x * 8 + wave * 2 + grp;   // grid 12500
    const float4* h4 = (const float4*)h;
    const float4* g4 = (const float4*)grad;

    float myinfo = 0.f;
    {
        const int gid = blockIdx.x * 256 + tid;
        if (gid < NM * DD) myinfo = b[gid & 127] * grad[gid];
    }

    const int s0 = rs[row], s1 = rs[row + 1];
    const int cnt = s1 - s0;

    const float4 hd = h4[(size_t)row * 32 + l];
    float4 acc = ((const float4*)b)[l];
    int sv = 0; float wv = 0.f;
    if (l < cnt) {
        const int2 e = eq[s0 + l];
        sv = e.x; wv = __int_as_float(e.y);
    }

    float4 gacc = make_float4(0.f, 0.f, 0.f, 0.f);
    const int nb = (cnt < 32) ? cnt : 32;
    int i = 0;
    for (; i + 4 <= nb; i += 4) {
        const int sr0 = __shfl(sv, gb + i),     sr1 = __shfl(sv, gb + i + 1);
        const int sr2 = __shfl(sv, gb + i + 2), sr3 = __shfl(sv, gb + i + 3);
        const float w0 = __shfl(wv, gb + i),     w1 = __shfl(wv, gb + i + 1);
        const float w2 = __shfl(wv, gb + i + 2), w3 = __shfl(wv, gb + i + 3);
        const float4 h0 = h4[(size_t)sr0 * 32 + l];
        const float4 h1 = h4[(size_t)sr1 * 32 + l];
        const float4 hv2 = h4[(size_t)sr2 * 32 + l];
        const float4 h3 = h4[(size_t)sr3 * 32 + l];
        const int m0 = sr0 - BN, m1 = sr1 - BN, m2 = sr2 - BN, m3 = sr3 - BN;
        const float4 g0 = g4[(size_t)max(m0, 0) * 32 + l];
        const float4 g1 = g4[(size_t)max(m1, 0) * 32 + l];
        const float4 gv2 = g4[(size_t)max(m2, 0) * 32 + l];
        const float4 g3 = g4[(size_t)max(m3, 0) * 32 + l];
        acc.x += w0 * h0.x + w1 * h1.x + w2 * hv2.x + w3 * h3.x;
        acc.y += w0 * h0.y + w1 * h1.y + w2 * hv2.y + w3 * h3.y;
        acc.z += w0 * h0.z + w1 * h1.z + w2 * hv2.z + w3 * h3.z;
        acc.w += w0 * h0.w + w1 * h1.w + w2 * hv2.w + w3 * h3.w;
        const float gw0 = (m0 >= 0) ? w0 : 0.f, gw1 = (m1 >= 0) ? w1 : 0.f;
        const float gw2 = (m2 >= 0) ? w2 : 0.f, gw3 = (m3 >= 0) ? w3 : 0.f;
        gacc.x += gw0 * g0.x + gw1 * g1.x + gw2 * gv2.x + gw3 * g3.x;
        gacc.y += gw0 * g0.y + gw1 * g1.y + gw2 * gv2.y + gw3 * g3.y;
        gacc.z += gw0 * g0.z + gw1 * g1.z + gw2 * gv2.z + gw3 * g3.z;
        gacc.w += gw0 * g0.w + gw1 * g1.w + gw2 * gv2.w + gw3 * g3.w;
    }
    for (; i < nb; i++) {
        const int sr = __shfl(sv, gb + i);
        const float w = __shfl(wv, gb + i);
        const float4 hv = h4[(size_t)sr * 32 + l];
        acc.x += w * hv.x; acc.y += w * hv.y; acc.z += w * hv.z; acc.w += w * hv.w;
        const int m = sr - BN;
        const float4 gv = g4[(size_t)max(m, 0) * 32 + l];
        const float gw = (m >= 0) ? w : 0.f;
        gacc.x += gw * gv.x; gacc.y += gw * gv.y; gacc.z += gw * gv.z; gacc.w += gw * gv.w;
    }
    for (int j = s0 + 32; j < s1; j++) {
        const int2 e = eq[j];
        const int sr = e.x; const float w = __int_as_float(e.y);
        const float4 hv = h4[(size_t)sr * 32 + l];
        acc.x += w * hv.x; acc.y += w * hv.y; acc.z += w * hv.z; acc.w += w * hv.w;
        const int m = sr - BN;
        const float4 gv = g4[(size_t)max(m, 0) * 32 + l];
        const float gw = (m >= 0) ? w : 0.f;
        gacc.x += gw * gv.x; gacc.y += gw * gv.y; gacc.z += gw * gv.z; gacc.w += gw * gv.w;
    }

    ((float4*)out)[(size_t)row * 32 + l] = acc;
    myinfo += hd.x * gacc.x + hd.y * gacc.y + hd.z * gacc.z + hd.w * gacc.w;
#pragma unroll
    for (int off = 32; off > 0; off >>= 1) myinfo += __shfl_down(myinfo, off);
    __shared__ float li[4];
    __shared__ int lastblk;
    if (lane == 0) li[wave] = myinfo;
    __syncthreads();
    if (tid == 0) {
        unsafeAtomicAdd(&islots[blockIdx.x & 255], li[0] + li[1] + li[2] + li[3]);
        __threadfence();
        lastblk = (atomicAdd(&ctrs[1], 1) == AGG_NB - 1);
    }
    __syncthreads();
    if (lastblk) {
        // agent-scope atomic reads bypass potentially-stale L1/L2 lines
        float v = __hip_atomic_load(&slots[tid], __ATOMIC_RELAXED, __HIP_MEMORY_SCOPE_AGENT);
        float u2 = __hip_atomic_load(&islots[tid], __ATOMIC_RELAXED, __HIP_MEMORY_SCOPE_AGENT);
#pragma unroll
        for (int off = 32; off > 0; off >>= 1) {
            v += __shfl_down(v, off);
            u2 += __shfl_down(u2, off);
        }
        __shared__ float lv[4], lu[4];
        if ((tid & 63) == 0) { lv[tid >> 6] = v; lu[tid >> 6] = u2; }
        __syncthreads();
        if (tid == 0) {
            float* out_tail = out + (size_t)BN * DD;
            out_tail[0] = (lv[0] + lv[1] + lv[2] + lv[3]) / (float)BN;
            out_tail[1] = (lu[0] + lu[1] + lu[2] + lu[3]) * warm[0];
        }
    }
}

extern "C" void kernel_launch(void* const* d_in, const int* in_sizes, int n_in,
                              void* d_out, int out_size, void* d_ws, size_t ws_size,
                              hipStream_t stream) {
    const float* X_B      = (const float*)d_in[0];
    const int*   edge_dst = (const int*)d_in[1];
    const int*   edge_src = (const int*)d_in[2];
    const float* ew       = (const float*)d_in[3];
    const int*   cidx     = (const int*)d_in[5];
    const float* codebook = (const float*)d_in[6];
    const float* grad     = (const float*)d_in[7];
    const float* W        = (const float*)d_in[8];
    const float* b        = (const float*)d_in[9];
    const float* warm     = (const float*)d_in[10];
    float* out = (float*)d_out;
    float* ws  = (float*)d_ws;

    float*  h      = ws + OFF_H;
    int*    cnt    = (int*)(ws + OFF_CNT);
    float*  slots  = ws + OFF_SLOTS;
    float*  islots = ws + OFF_ISLOTS;
    int*    rs     = (int*)(ws + OFF_RS);
    int*    next   = (int*)(ws + OFF_NEXT);
    int2*   eq     = (int2*)(ws + OFF_EQ);
    int*    ctrs   = (int*)(ws + OFF_BS);
    short8* wpk    = (short8*)(ws + OFF_WP);
    unsigned long long* st = (unsigned long long*)(ws + OFF_ST);

    k_prep<<<100, 256, 0, stream>>>(W, wpk, (int4*)cnt, st, ctrs);
    k_gemm<<<GEMM_NB + HIST_NB, 256, 0, stream>>>(X_B, codebook, wpk, warm, h, slots,
                                                  edge_dst, cnt);
    k_scan<<<SNB, 256, 0, stream>>>(cnt, rs, next, st);
    k_slot<<<(EN + 255) / 256, 256, 0, stream>>>(edge_dst, edge_src, ew, cidx, next, eq);
    k_agg<<<AGG_NB, 256, 0, stream>>>(h, rs, eq, b, grad, out, islots,
                                      slots, warm, ctrs);
}

// Round 12
// 239.285 us; speedup vs baseline: 2.6641x; 2.6641x over previous
//
#include <hip/hip_runtime.h>

#define BN 100000
#define DD 128
#define EN 500000
#define NM 4096
#define NROWS (BN + NM)     // 104096
#define GEMM_NB ((NROWS + 63) / 64)       // 1627 gemm blocks (64 rows each)
#define HIST_NB ((EN / 4 + 255) / 256)    // 489 hist blocks (fused in gemm tail)
#define SCHUNK 1024
#define SNB ((BN + SCHUNK - 1) / SCHUNK)  // 98 scan blocks (all co-resident)
#define AGG_NB (BN / 8)                   // 12500 aggregate blocks

// ---- ws layout (4-byte units) ----
#define OFF_H      0
#define LEN_H      ((size_t)NROWS * DD)           // 13,324,288
#define OFF_CNT    (LEN_H)                        // 100000 ints (zeroed by k_prep)
#define OFF_SLOTS  (OFF_CNT + BN)                 // 256 f xbnorm
#define OFF_ISLOTS (OFF_SLOTS + 256)              // 256 f info
#define OFF_RS     (OFF_ISLOTS + 256)             // 100001 ints
#define OFF_NEXT   (OFF_RS + BN + 1)              // 100000 ints
#define OFF_EQ     ((OFF_NEXT + BN + 1) & ~(size_t)1)  // int2[EN], 8B-aligned
#define OFF_BS     (OFF_EQ + 2 * (size_t)EN)      // 128 ints (ctrs, unused now)
// packed W (16384 f) + lookback state (98 ull) live INSIDE the eq region:
// written early, dead before slot-scatter writes eq. Zero ws growth.
#define OFF_WP     ((OFF_EQ + 3) & ~(size_t)3)
#define OFF_ST     (OFF_WP + 16384)

typedef __attribute__((ext_vector_type(8))) short short8;      // 8 bf16 = 4 VGPR
typedef __attribute__((ext_vector_type(16))) float f32x16;     // MFMA 32x32 acc

// split fp32 -> bf16 hi (truncate) + bf16 lo (RNE of residual); pack pairs.
__device__ __forceinline__ void split2(float x0, float x1, unsigned& hi, unsigned& lo) {
    const unsigned b0 = __float_as_uint(x0), b1 = __float_as_uint(x1);
    const unsigned h0 = b0 & 0xFFFF0000u, h1 = b1 & 0xFFFF0000u;
    hi = (h0 >> 16) | h1;
    const float r0 = x0 - __uint_as_float(h0);
    const float r1 = x1 - __uint_as_float(h1);
    unsigned c0 = __float_as_uint(r0), c1 = __float_as_uint(r1);
    c0 += 0x7FFFu + ((c0 >> 16) & 1u);
    c1 += 0x7FFFu + ((c1 >> 16) & 1u);
    lo = (c0 >> 16) | (c1 & 0xFFFF0000u);
}

// ---------------- prep: zero cnt/slots/islots + scan state; pack W ----------
__global__ void k_prep(const float* __restrict__ W, short8* __restrict__ wp,
                       int4* __restrict__ zero_base, unsigned long long* __restrict__ st,
                       int* __restrict__ ctrs) {
    const int gid = blockIdx.x * 256 + threadIdx.x;
    if (gid < (BN + 512) / 4) zero_base[gid] = make_int4(0, 0, 0, 0);
    if (gid < SNB) st[gid] = 0ULL;
    if (gid == 0) { ctrs[0] = 0; ctrs[1] = 0; }
    if (gid < 2048) {
        const int lane_c = gid & 63;
        const int ct_c = (gid >> 6) & 3;
        const int ks_c = (gid >> 8) & 7;
        const int col = ct_c * 32 + (lane_c & 31);
        const int kb = ks_c * 16 + (lane_c >> 5) * 8;
        union { unsigned u[4]; short8 v; } uh, ul;
#pragma unroll
        for (int j2 = 0; j2 < 4; j2++) {
            const float x0 = W[(size_t)(kb + 2 * j2) * DD + col];
            const float x1 = W[(size_t)(kb + 2 * j2 + 1) * DD + col];
            split2(x0, x1, uh.u[j2], ul.u[j2]);
        }
        wp[((0 * 8 + ks_c) * 4 + ct_c) * 64 + lane_c] = uh.v;
        wp[((1 * 8 + ks_c) * 4 + ct_c) * 64 + lane_c] = ul.v;
    }
}

// ---------------- GEMM via split-bf16 MFMA + fused xb_norm + fused hist tail
// Per-wave tile 32 rows x 64 cols (acc = 32 AGPR); block = 64 rows x 128 cols.
// A fp32-staged 4 K-steps deep; B from pre-packed global Wp (L2-resident).
__launch_bounds__(256, 4)
__global__ void k_gemm(const float* __restrict__ X_B, const float* __restrict__ codebook,
                       const short8* __restrict__ wp, const float* __restrict__ warm,
                       float* __restrict__ h, float* __restrict__ slots,
                       const int* __restrict__ edge_dst, int* __restrict__ cnt) {
    if (blockIdx.x >= GEMM_NB) {
        // ---- histogram by dst (int4), block-uniform branch, no barriers ----
        const int e4 = (blockIdx.x - GEMM_NB) * 256 + threadIdx.x;
        if (e4 < EN / 4) {
            const int4 d = ((const int4*)edge_dst)[e4];
            atomicAdd(&cnt[d.x], 1);
            atomicAdd(&cnt[d.y], 1);
            atomicAdd(&cnt[d.z], 1);
            atomicAdd(&cnt[d.w], 1);
        }
        return;
    }

    const int tid = threadIdx.x;
    const float wu = *warm;
    const int lane = tid & 63;
    const int w = tid >> 6;
    const int ch = w & 1;
    const int r0 = blockIdx.x * 64;
    const int rw0 = r0 + (w >> 1) * 32;
    const int rr = lane & 31;
    const int kh = lane >> 5;
    const int row = rw0 + rr;

    const bool is_x = (row < BN);
    const bool valid = (row < NROWS);
    const float* src = is_x ? (X_B + (size_t)row * DD)
                            : (codebook + (size_t)(valid ? (row - BN) : 0) * DD);
    const float scale = is_x ? 1.f : (valid ? wu : 0.f);
    const float* srck = src + kh * 8;
    const short8* wpl = wp + lane;
    const int ct0 = ch * 2, ct1 = ch * 2 + 1;

    f32x16 acc0 = {}, acc1 = {};
    float ss = 0.f;

    float4 a[8];
#pragma unroll
    for (int i = 0; i < 8; i++)
        a[i] = *(const float4*)(srck + (i >> 1) * 16 + (i & 1) * 4);

#pragma unroll
    for (int ks = 0; ks < 8; ks++) {
        const int sl = (ks & 3) * 2;
        float4 q0 = a[sl], q1 = a[sl + 1];
        if (ks < 4) {
            a[sl]     = *(const float4*)(srck + (ks + 4) * 16);
            a[sl + 1] = *(const float4*)(srck + (ks + 4) * 16 + 4);
        }
        q0.x *= scale; q0.y *= scale; q0.z *= scale; q0.w *= scale;
        q1.x *= scale; q1.y *= scale; q1.z *= scale; q1.w *= scale;
        ss += q0.x * q0.x + q0.y * q0.y + q0.z * q0.z + q0.w * q0.w +
              q1.x * q1.x + q1.y * q1.y + q1.z * q1.z + q1.w * q1.w;

        union { unsigned u[4]; short8 v; } ah, al;
        split2(q0.x, q0.y, ah.u[0], al.u[0]);
        split2(q0.z, q0.w, ah.u[1], al.u[1]);
        split2(q1.x, q1.y, ah.u[2], al.u[2]);
        split2(q1.z, q1.w, ah.u[3], al.u[3]);

        const short8 bh0 = wpl[((0 * 8 + ks) * 4 + ct0) * 64];
        const short8 bh1 = wpl[((0 * 8 + ks) * 4 + ct1) * 64];
        const short8 bl0 = wpl[((1 * 8 + ks) * 4 + ct0) * 64];
        const short8 bl1 = wpl[((1 * 8 + ks) * 4 + ct1) * 64];

        acc0 = __builtin_amdgcn_mfma_f32_32x32x16_bf16(ah.v, bh0, acc0, 0, 0, 0);
        acc1 = __builtin_amdgcn_mfma_f32_32x32x16_bf16(ah.v, bh1, acc1, 0, 0, 0);
        acc0 = __builtin_amdgcn_mfma_f32_32x32x16_bf16(al.v, bh0, acc0, 0, 0, 0);
        acc1 = __builtin_amdgcn_mfma_f32_32x32x16_bf16(al.v, bh1, acc1, 0, 0, 0);
        acc0 = __builtin_amdgcn_mfma_f32_32x32x16_bf16(ah.v, bl0, acc0, 0, 0, 0);
        acc1 = __builtin_amdgcn_mfma_f32_32x32x16_bf16(ah.v, bl1, acc1, 0, 0, 0);
        acc0 = __builtin_amdgcn_mfma_f32_32x32x16_bf16(al.v, bl0, acc0, 0, 0, 0);
        acc1 = __builtin_amdgcn_mfma_f32_32x32x16_bf16(al.v, bl1, acc1, 0, 0, 0);
    }

    const int colbase = ch * 64 + (lane & 31);
    const int mbase = 4 * (lane >> 5);
    const bool fullblk = (r0 + 64 <= NROWS);
    if (fullblk) {
#pragma unroll
        for (int r = 0; r < 16; r++) {
            const int m = (r & 3) + 8 * (r >> 2) + mbase;
            float* hp = &h[(size_t)(rw0 + m) * DD + colbase];
            hp[0]  = acc0[r];
            hp[32] = acc1[r];
        }
    } else {
#pragma unroll
        for (int r = 0; r < 16; r++) {
            const int m = (r & 3) + 8 * (r >> 2) + mbase;
            if (rw0 + m < NROWS) {
                float* hp = &h[(size_t)(rw0 + m) * DD + colbase];
                hp[0]  = acc0[r];
                hp[32] = acc1[r];
            }
        }
    }

    float p = ss + __shfl_xor(ss, 32);
    float local = 0.f;
    if (ch == 0 && lane < 32 && row < BN) local = sqrtf(p);
#pragma unroll
    for (int off = 32; off > 0; off >>= 1) local += __shfl_down(local, off);
    if (lane == 0 && ch == 0) unsafeAtomicAdd(&slots[blockIdx.x & 255], local);
}

// ---------------- single-pass decoupled-lookback scan (replaces scan1/2/3) ----
// 98 blocks (all co-resident by capacity => progress guaranteed regardless of
// dispatch order). Block b scans cnt[b*1024..], publishes {state,value} packed
// in one 64-bit agent-scope atomic; spins only on lower-ID blocks.
__launch_bounds__(256)
__global__ void k_scan(const int* __restrict__ cnt, int* __restrict__ rs,
                       int* __restrict__ next, unsigned long long* __restrict__ st) {
    const int bid = blockIdx.x, tid = threadIdx.x;
    const int i0 = bid * SCHUNK + tid * 4;
    int4 v = make_int4(0, 0, 0, 0);
    if (i0 + 3 < BN) {
        v = *(const int4*)&cnt[i0];
    } else if (i0 < BN) {
        v.x = cnt[i0];
        if (i0 + 1 < BN) v.y = cnt[i0 + 1];
        if (i0 + 2 < BN) v.z = cnt[i0 + 2];
    }
    const int tsum = v.x + v.y + v.z + v.w;

    // inclusive wave scan of per-thread sums
    int s = tsum;
#pragma unroll
    for (int off = 1; off < 64; off <<= 1) {
        const int n = __shfl_up(s, off);
        if ((tid & 63) >= off) s += n;
    }
    __shared__ int wsum[4];
    __shared__ int sprefix;
    if ((tid & 63) == 63) wsum[tid >> 6] = s;
    __syncthreads();
    int woff = 0;
    {
        const int wv = tid >> 6;
        if (wv > 0) woff += wsum[0];
        if (wv > 1) woff += wsum[1];
        if (wv > 2) woff += wsum[2];
    }
    if (tid == 0) {
        const int total = wsum[0] + wsum[1] + wsum[2] + wsum[3];
        const unsigned long long pkt = (bid == 0)
            ? ((2ULL << 32) | (unsigned)total)
            : ((1ULL << 32) | (unsigned)total);
        __hip_atomic_store(&st[bid], pkt, __ATOMIC_RELAXED, __HIP_MEMORY_SCOPE_AGENT);
        int run = 0;
        if (bid > 0) {
            int pb = bid - 1;
            while (true) {
                const unsigned long long q = __hip_atomic_load(
                    &st[pb], __ATOMIC_RELAXED, __HIP_MEMORY_SCOPE_AGENT);
                const unsigned stt = (unsigned)(q >> 32);
                if (stt == 0u) { __builtin_amdgcn_s_sleep(1); continue; }
                run += (int)(q & 0xffffffffULL);
                if (stt == 2u) break;
                --pb;
            }
            __hip_atomic_store(&st[bid], (2ULL << 32) | (unsigned)(run + total),
                               __ATOMIC_RELAXED, __HIP_MEMORY_SCOPE_AGENT);
        }
        sprefix = run;
    }
    __syncthreads();
    const int ex = sprefix + woff + (s - tsum);
    const int e0 = ex, e1 = ex + v.x, e2 = e1 + v.y, e3 = e2 + v.z;
    if (i0 < BN)     { rs[i0]     = e0; next[i0]     = e0; }
    if (i0 + 1 < BN) { rs[i0 + 1] = e1; next[i0 + 1] = e1; }
    if (i0 + 2 < BN) { rs[i0 + 2] = e2; next[i0 + 2] = e2; }
    if (i0 + 3 < BN) { rs[i0 + 3] = e3; next[i0 + 3] = e3; }
    if (bid == 0 && tid == 0) rs[BN] = EN;
}

// ---------------- slot-scatter edges into CSR order (packed int2) --------
__global__ void k_slot(const int* __restrict__ edge_dst, const int* __restrict__ edge_src,
                       const float* __restrict__ ew, const int* __restrict__ cidx,
                       int* __restrict__ next, int2* __restrict__ eq) {
    const int e = blockIdx.x * 256 + threadIdx.x;
    if (e < EN) {
        const int d = edge_dst[e];
        const int s = edge_src[e];
        const int p = atomicAdd(&next[d], 1);
        const int se = (s < BN) ? s : (BN + cidx[s]);
        eq[p] = make_int2(se, __float_as_int(ew[e]));
    }
}

// ---------------- fused aggregate + info (R7-exact: NO fence, NO finalize) ----
// 2 rows per wave (32-lane groups), float4 per lane: 2 independent edge
// chains + 4-deep unroll => 16 concurrent gathers/wave.
// NOTE: __threadfence() per block here cost 9x (L2 writeback storm, R11).
__launch_bounds__(256)
__global__ void k_agg(const float* __restrict__ h, const int* __restrict__ rs,
                      const int2* __restrict__ eq,
                      const float* __restrict__ b, const float* __restrict__ grad,
                      float* __restrict__ out, float* __restrict__ islots) {
    const int lane = threadIdx.x & 63;
    const int wave = threadIdx.x >> 6;
    const int grp  = lane >> 5;
    const int l    = lane & 31;
    const int gb   = grp << 5;
    const int row  = blockIdx.x * 8 + wave * 2 + grp;   // grid 12500
    const float4* h4 = (const float4*)h;
    const float4* g4 = (const float4*)grad;

    float myinfo = 0.f;
    {
        const int gid = blockIdx.x * 256 + threadIdx.x;
        if (gid < NM * DD) myinfo = b[gid & 127] * grad[gid];
    }

    const int s0 = rs[row], s1 = rs[row + 1];
    const int cnt = s1 - s0;

    const float4 hd = h4[(size_t)row * 32 + l];
    float4 acc = ((const float4*)b)[l];
    int sv = 0; float wv = 0.f;
    if (l < cnt) {
        const int2 e = eq[s0 + l];
        sv = e.x; wv = __int_as_float(e.y);
    }

    float4 gacc = make_float4(0.f, 0.f, 0.f, 0.f);
    const int nb = (cnt < 32) ? cnt : 32;
    int i = 0;
    for (; i + 4 <= nb; i += 4) {
        const int sr0 = __shfl(sv, gb + i),     sr1 = __shfl(sv, gb + i + 1);
        const int sr2 = __shfl(sv, gb + i + 2), sr3 = __shfl(sv, gb + i + 3);
        const float w0 = __shfl(wv, gb + i),     w1 = __shfl(wv, gb + i + 1);
        const float w2 = __shfl(wv, gb + i + 2), w3 = __shfl(wv, gb + i + 3);
        const float4 h0 = h4[(size_t)sr0 * 32 + l];
        const float4 h1 = h4[(size_t)sr1 * 32 + l];
        const float4 hv2 = h4[(size_t)sr2 * 32 + l];
        const float4 h3 = h4[(size_t)sr3 * 32 + l];
        const int m0 = sr0 - BN, m1 = sr1 - BN, m2 = sr2 - BN, m3 = sr3 - BN;
        const float4 g0 = g4[(size_t)max(m0, 0) * 32 + l];
        const float4 g1 = g4[(size_t)max(m1, 0) * 32 + l];
        const float4 gv2 = g4[(size_t)max(m2, 0) * 32 + l];
        const float4 g3 = g4[(size_t)max(m3, 0) * 32 + l];
        acc.x += w0 * h0.x + w1 * h1.x + w2 * hv2.x + w3 * h3.x;
        acc.y += w0 * h0.y + w1 * h1.y + w2 * hv2.y + w3 * h3.y;
        acc.z += w0 * h0.z + w1 * h1.z + w2 * hv2.z + w3 * h3.z;
        acc.w += w0 * h0.w + w1 * h1.w + w2 * hv2.w + w3 * h3.w;
        const float gw0 = (m0 >= 0) ? w0 : 0.f, gw1 = (m1 >= 0) ? w1 : 0.f;
        const float gw2 = (m2 >= 0) ? w2 : 0.f, gw3 = (m3 >= 0) ? w3 : 0.f;
        gacc.x += gw0 * g0.x + gw1 * g1.x + gw2 * gv2.x + gw3 * g3.x;
        gacc.y += gw0 * g0.y + gw1 * g1.y + gw2 * gv2.y + gw3 * g3.y;
        gacc.z += gw0 * g0.z + gw1 * g1.z + gw2 * gv2.z + gw3 * g3.z;
        gacc.w += gw0 * g0.w + gw1 * g1.w + gw2 * gv2.w + gw3 * g3.w;
    }
    for (; i < nb; i++) {
        const int sr = __shfl(sv, gb + i);
        const float w = __shfl(wv, gb + i);
        const float4 hv = h4[(size_t)sr * 32 + l];
        acc.x += w * hv.x; acc.y += w * hv.y; acc.z += w * hv.z; acc.w += w * hv.w;
        const int m = sr - BN;
        const float4 gv = g4[(size_t)max(m, 0) * 32 + l];
        const float gw = (m >= 0) ? w : 0.f;
        gacc.x += gw * gv.x; gacc.y += gw * gv.y; gacc.z += gw * gv.z; gacc.w += gw * gv.w;
    }
    for (int j = s0 + 32; j < s1; j++) {
        const int2 e = eq[j];
        const int sr = e.x; const float w = __int_as_float(e.y);
        const float4 hv = h4[(size_t)sr * 32 + l];
        acc.x += w * hv.x; acc.y += w * hv.y; acc.z += w * hv.z; acc.w += w * hv.w;
        const int m = sr - BN;
        const float4 gv = g4[(size_t)max(m, 0) * 32 + l];
        const float gw = (m >= 0) ? w : 0.f;
        gacc.x += gw * gv.x; gacc.y += gw * gv.y; gacc.z += gw * gv.z; gacc.w += gw * gv.w;
    }

    ((float4*)out)[(size_t)row * 32 + l] = acc;
    myinfo += hd.x * gacc.x + hd.y * gacc.y + hd.z * gacc.z + hd.w * gacc.w;
#pragma unroll
    for (int off = 32; off > 0; off >>= 1) myinfo += __shfl_down(myinfo, off);
    __shared__ float li[4];
    if (lane == 0) li[wave] = myinfo;
    __syncthreads();
    if (threadIdx.x == 0)
        unsafeAtomicAdd(&islots[blockIdx.x & 255], li[0] + li[1] + li[2] + li[3]);
}

// ---------------- finalize scalars (separate launch; kernel boundary = sync) --
__global__ void k_finalize(const float* __restrict__ slots, const float* __restrict__ islots,
                           const float* __restrict__ warm, float* __restrict__ out_tail) {
    float v = slots[threadIdx.x];
    float u = islots[threadIdx.x];
#pragma unroll
    for (int off = 32; off > 0; off >>= 1) {
        v += __shfl_down(v, off);
        u += __shfl_down(u, off);
    }
    __shared__ float lv[4], lu[4];
    if ((threadIdx.x & 63) == 0) { lv[threadIdx.x >> 6] = v; lu[threadIdx.x >> 6] = u; }
    __syncthreads();
    if (threadIdx.x == 0) {
        out_tail[0] = (lv[0] + lv[1] + lv[2] + lv[3]) / (float)BN;
        out_tail[1] = (lu[0] + lu[1] + lu[2] + lu[3]) * warm[0];
    }
}

extern "C" void kernel_launch(void* const* d_in, const int* in_sizes, int n_in,
                              void* d_out, int out_size, void* d_ws, size_t ws_size,
                              hipStream_t stream) {
    const float* X_B      = (const float*)d_in[0];
    const int*   edge_dst = (const int*)d_in[1];
    const int*   edge_src = (const int*)d_in[2];
    const float* ew       = (const float*)d_in[3];
    const int*   cidx     = (const int*)d_in[5];
    const float* codebook = (const float*)d_in[6];
    const float* grad     = (const float*)d_in[7];
    const float* W        = (const float*)d_in[8];
    const float* b        = (const float*)d_in[9];
    const float* warm     = (const float*)d_in[10];
    float* out = (float*)d_out;
    float* ws  = (float*)d_ws;

    float*  h      = ws + OFF_H;
    int*    cnt    = (int*)(ws + OFF_CNT);
    float*  slots  = ws + OFF_SLOTS;
    float*  islots = ws + OFF_ISLOTS;
    int*    rs     = (int*)(ws + OFF_RS);
    int*    next   = (int*)(ws + OFF_NEXT);
    int2*   eq     = (int2*)(ws + OFF_EQ);
    int*    ctrs   = (int*)(ws + OFF_BS);
    short8* wpk    = (short8*)(ws + OFF_WP);
    unsigned long long* st = (unsigned long long*)(ws + OFF_ST);

    k_prep<<<100, 256, 0, stream>>>(W, wpk, (int4*)cnt, st, ctrs);
    k_gemm<<<GEMM_NB + HIST_NB, 256, 0, stream>>>(X_B, codebook, wpk, warm, h, slots,
                                                  edge_dst, cnt);
    k_scan<<<SNB, 256, 0, stream>>>(cnt, rs, next, st);
    k_slot<<<(EN + 255) / 256, 256, 0, stream>>>(edge_dst, edge_src, ew, cidx, next, eq);
    k_agg<<<AGG_NB, 256, 0, stream>>>(h, rs, eq, b, grad, out, islots);
    k_finalize<<<1, 256, 0, stream>>>(slots, islots, warm, out + (size_t)BN * DD);
}